// Round 7
// baseline (102.050 us; speedup 1.0000x reference)
//
#include <hip/hip_runtime.h>
#include <hip/hip_fp16.h>

// SurfEval: B=8, M=128, N=128, ctrl 4ch, P=Q=3, OUT=512
// ctrl_pts : (8,128,128,4) f32; Nu/Nv: (512,512,4) f32; spans: (512,512) i32 in [3,127]
// out : (8,512,512,3) f32 = sw[...,:3]/sw[...,3:]
//
// Round-7 plan: bin uv by exact us (125 bins) x 8 contiguous-uv tiles.
// Per (bin,tile) block: stage 4 ctrl rows (32 KB fp16, layout (m,n,b)) in LDS,
// stream 4-byte records {uv_local,vs3}, gather patch from LDS (imm offsets),
// write outputs scattered within the tile's 3 MB window (XCD-pinned via bid&7).

#define OUTD 512
#define UVN  (OUTD * OUTD)   // 262144
#define MD   128
#define ND   128
#define BD   8
#define TILES 8
#define TSH   15             // 32768 uv per tile
#define BIN2  125
#define CELLS (BIN2 * TILES) // 1000
#define CAP2  1024           // slots/cell; mean 262 -> overflow impossible

// ws layout
#define WS_CTRLH 0                         // 1 MB   (m,n,b) half4
#define WS_CURS  (1u << 20)                // 4 KB
#define WS_REC   ((1u << 20) + (1u << 16)) // 4 MB records
#define WS_NEED  (WS_REC + (size_t)CELLS * CAP2 * 4)

// ---------- transpose+convert: ctrl (b,m,n,4f32) -> ctrlH (m,n,b,4f16) ----------
__global__ __launch_bounds__(256) void transpose_h_kernel(
    const float4* __restrict__ ctrl, ushort4* __restrict__ ctrlH)
{
    const int tid = blockIdx.x * blockDim.x + threadIdx.x;  // 0 .. 131071
    const int b   = tid & 7;
    const int mn  = tid >> 3;
    const float4 c = ctrl[b * (MD * ND) + mn];
    ushort4 h;
    h.x = __half_as_ushort(__float2half(c.x));
    h.y = __half_as_ushort(__float2half(c.y));
    h.z = __half_as_ushort(__float2half(c.z));
    h.w = __half_as_ushort(__float2half(c.w));
    ctrlH[tid] = h;
}

__global__ void zero_cursors_kernel(int* c)
{
    const int i = blockIdx.x * blockDim.x + threadIdx.x;
    if (i < CELLS) c[i] = 0;
}

// ---------- builder: 4-byte records, cell = us3*8 + tile ----------
__global__ __launch_bounds__(256) void build2_kernel(
    const int* __restrict__ uspan,
    const int* __restrict__ vspan,
    int* __restrict__ curs,
    unsigned int* __restrict__ recs)
{
    const int uv  = blockIdx.x * 256 + threadIdx.x;
    const int us3 = uspan[uv] - 3;          // 0..124
    const int vs3 = vspan[uv] - 3;          // 0..124
    const int tile = uv >> TSH;
    const int cell = us3 * TILES + tile;
    const int slot = atomicAdd(&curs[cell], 1);
    if (slot < CAP2)
        recs[cell * CAP2 + slot] =
            (unsigned int)(uv & ((1 << TSH) - 1)) | ((unsigned int)vs3 << TSH);
}

// ---------- eval: one block per (bin,tile); patch gather from LDS ----------
__global__ __launch_bounds__(256) void eval2_kernel(
    const uint2* __restrict__ ctrlH,
    const float4* __restrict__ Nu4,
    const float4* __restrict__ Nv4,
    const unsigned int* __restrict__ recs,
    const int* __restrict__ curs,
    float* __restrict__ out)
{
    __shared__ uint2 lds[4096];   // rows us3..us3+3, (l,n,b) -> l*1024+n*8+b; 32 KB

    const int bin  = blockIdx.x >> 3;
    const int tile = blockIdx.x & 7;        // low bits -> XCD round-robin pin
    const int cell = bin * TILES + tile;
    const int count = min(curs[cell], CAP2);
    if (count == 0) return;                 // uniform per block

    // stage 4 contiguous ctrl rows: ctrlH[bin*1024 .. bin*1024+4096)
    const uint2* src = ctrlH + bin * 1024;
    #pragma unroll
    for (int i = 0; i < 16; ++i)
        lds[threadIdx.x + 256 * i] = src[threadIdx.x + 256 * i];
    __syncthreads();

    const int b = threadIdx.x & 7;
    const int g = threadIdx.x >> 3;         // 0..31
    const unsigned int* rc = recs + (size_t)cell * CAP2;

    for (int s = g; s < count; s += 32) {
        const unsigned int rec = rc[s];
        const int uvl = rec & ((1 << TSH) - 1);
        const int vs3 = rec >> TSH;
        const int uv  = (tile << TSH) | uvl;

        const float4 nu = Nu4[uv];          // 8 lanes share -> broadcast
        const float4 nv = Nv4[uv];
        const float nuL[4] = {nu.x, nu.y, nu.z, nu.w};
        const float nvL[4] = {nv.x, nv.y, nv.z, nv.w};

        const uint2* p = lds + vs3 * 8 + b; // all 16 reads: imm offsets
        float ax = 0.f, ay = 0.f, az = 0.f, aw = 0.f;
        #pragma unroll
        for (int l = 0; l < 4; ++l) {
            #pragma unroll
            for (int r = 0; r < 4; ++r) {
                const uint2 h = p[l * 1024 + r * 8];
                const float w = nuL[l] * nvL[r];
                const __half2 h01 = *(const __half2*)(&h.x);
                const __half2 h23 = *(const __half2*)(&h.y);
                const float2 xy = __half22float2(h01);
                const float2 zw = __half22float2(h23);
                ax = fmaf(w, xy.x, ax);
                ay = fmaf(w, xy.y, ay);
                az = fmaf(w, zw.x, az);
                aw = fmaf(w, zw.y, aw);
            }
        }
        const float inv = 1.0f / aw;
        float* o = out + ((size_t)b * UVN + uv) * 3;
        o[0] = ax * inv;
        o[1] = ay * inv;
        o[2] = az * inv;
    }
}

// ---------- fallback (verified round-1 kernel, no workspace needed) ----------
__global__ __launch_bounds__(256) void surfeval_naive_kernel(
    const float* __restrict__ ctrl,
    const float* __restrict__ Nu,
    const float* __restrict__ Nv,
    const int* __restrict__ uspan,
    const int* __restrict__ vspan,
    float* __restrict__ out)
{
    const int tid = blockIdx.x * blockDim.x + threadIdx.x;
    const int uv = tid & (UVN - 1);
    const int b  = tid >> 18;

    const int us = uspan[uv];
    const int vs = vspan[uv];
    const float4 nu = reinterpret_cast<const float4*>(Nu)[uv];
    const float4 nv = reinterpret_cast<const float4*>(Nv)[uv];
    const float nuL[4] = {nu.x, nu.y, nu.z, nu.w};
    const float nvL[4] = {nv.x, nv.y, nv.z, nv.w};

    const float4* cp = reinterpret_cast<const float4*>(ctrl)
                     + ((b * MD + (us - 3)) * ND + (vs - 3));
    float ax = 0.f, ay = 0.f, az = 0.f, aw = 0.f;
    #pragma unroll
    for (int l = 0; l < 4; ++l) {
        const float4* row = cp + l * ND;
        #pragma unroll
        for (int r = 0; r < 4; ++r) {
            const float w = nuL[l] * nvL[r];
            const float4 cc = row[r];
            ax = fmaf(w, cc.x, ax); ay = fmaf(w, cc.y, ay);
            az = fmaf(w, cc.z, az); aw = fmaf(w, cc.w, aw);
        }
    }
    const float inv = 1.0f / aw;
    float* o = out + (size_t)tid * 3;
    o[0] = ax * inv; o[1] = ay * inv; o[2] = az * inv;
}

extern "C" void kernel_launch(void* const* d_in, const int* in_sizes, int n_in,
                              void* d_out, int out_size, void* d_ws, size_t ws_size,
                              hipStream_t stream) {
    const float* ctrl  = (const float*)d_in[0];
    const float* Nu    = (const float*)d_in[1];
    const float* Nv    = (const float*)d_in[2];
    const int*   uspan = (const int*)d_in[3];
    const int*   vspan = (const int*)d_in[4];
    float* out = (float*)d_out;

    if (ws_size >= WS_NEED) {
        char* ws = (char*)d_ws;
        ushort4*      ctrlH = (ushort4*)(ws + WS_CTRLH);
        int*          curs  = (int*)(ws + WS_CURS);
        unsigned int* recs  = (unsigned int*)(ws + WS_REC);

        transpose_h_kernel<<<(MD * ND * BD) / 256, 256, 0, stream>>>(
            (const float4*)ctrl, ctrlH);
        zero_cursors_kernel<<<(CELLS + 255) / 256, 256, 0, stream>>>(curs);
        build2_kernel<<<UVN / 256, 256, 0, stream>>>(uspan, vspan, curs, recs);
        eval2_kernel<<<CELLS, 256, 0, stream>>>(
            (const uint2*)ctrlH, (const float4*)Nu, (const float4*)Nv,
            recs, curs, out);
    } else {
        surfeval_naive_kernel<<<(BD * UVN) / 256, 256, 0, stream>>>(
            ctrl, Nu, Nv, uspan, vspan, out);
    }
}

// Round 8
// 100.024 us; speedup vs baseline: 1.0203x; 1.0203x over previous
//
#include <hip/hip_runtime.h>
#include <hip/hip_fp16.h>

// SurfEval: B=8, M=128, N=128, ctrl 4ch, P=Q=3, OUT=512
// out (8,512,512,3) f32 = sw[...,:3]/sw[...,3]
//
// Round-8: counting-sort points by (us3,vs3) cell (15625 cells, exact 2-pass
// compaction, padded atomics). evalA: patch-in-registers per cell, streams
// records, writes slot-ordered fp16 resbuf (1 line per record). evalB: gathers
// 1 line/point via invmap, stores coalesced (r5 machinery).

#define OUTD 512
#define UVN  (OUTD * OUTD)   // 262144
#define MD   128
#define ND   128
#define BD   8
#define SP   125             // span range
#define NCELL (SP * SP)      // 15625
#define PADI 16              // cursor pad: 16 dwords = 64 B/cell
#define SPLIT 2              // groups per cell in evalA

// ---------- shared helper: fp16 transpose ----------
__device__ __forceinline__ ushort4 cvt4h(const float4 c) {
    ushort4 h;
    h.x = __half_as_ushort(__float2half(c.x));
    h.y = __half_as_ushort(__float2half(c.y));
    h.z = __half_as_ushort(__float2half(c.z));
    h.w = __half_as_ushort(__float2half(c.w));
    return h;
}

// ---------- K1: transpose ctrl (b,m,n,4f32)->(m,n,b,4f16) + span histogram ----------
__global__ __launch_bounds__(256) void prep_kernel(
    const float4* __restrict__ ctrl, ushort4* __restrict__ ctrlH,
    const int* __restrict__ uspan, const int* __restrict__ vspan,
    int* __restrict__ hist)
{
    const int t = blockIdx.x * 256 + threadIdx.x;
    if (t < MD * ND * BD) {
        const int b  = t & 7;
        const int mn = t >> 3;
        ctrlH[t] = cvt4h(ctrl[b * (MD * ND) + mn]);
        return;
    }
    const int uv = t - MD * ND * BD;
    if (uv < UVN) {
        const int cell = (uspan[uv] - 3) * SP + (vspan[uv] - 3);
        atomicAdd(&hist[cell * PADI], 1);   // 64B-padded -> ~17 atomics/line
    }
}

// ---------- K2: exclusive scan of 15625 counts (1 block) ----------
__global__ __launch_bounds__(1024) void scan_kernel(
    const int* __restrict__ hist, int* __restrict__ base, int* __restrict__ curs)
{
    __shared__ int sd[1024];
    const int t = threadIdx.x;
    int cnt[16]; int sum = 0;
    #pragma unroll
    for (int k = 0; k < 16; ++k) {
        const int c = t * 16 + k;
        cnt[k] = (c < NCELL) ? hist[c * PADI] : 0;
        sum += cnt[k];
    }
    sd[t] = sum; __syncthreads();
    for (int d = 1; d < 1024; d <<= 1) {
        const int v = (t >= d) ? sd[t - d] : 0;
        __syncthreads();
        sd[t] += v;
        __syncthreads();
    }
    int run = sd[t] - sum;   // exclusive offset
    #pragma unroll
    for (int k = 0; k < 16; ++k) {
        const int c = t * 16 + k;
        if (c < NCELL) { base[c] = run; curs[c * PADI] = run; run += cnt[k]; }
    }
}

// ---------- K3: fill records (fp16 nu/nv) + invmap ----------
__global__ __launch_bounds__(256) void fill_kernel(
    const float4* __restrict__ Nu4, const float4* __restrict__ Nv4,
    const int* __restrict__ uspan, const int* __restrict__ vspan,
    int* __restrict__ curs, uint4* __restrict__ recW,
    unsigned int* __restrict__ invmap)
{
    const int uv = blockIdx.x * 256 + threadIdx.x;
    const int cell = (uspan[uv] - 3) * SP + (vspan[uv] - 3);
    const int slot = atomicAdd(&curs[cell * PADI], 1);  // exact: in [base, base+cnt)
    const float4 nu = Nu4[uv];
    const float4 nv = Nv4[uv];
    __half2 a = __floats2half2_rn(nu.x, nu.y);
    __half2 b = __floats2half2_rn(nu.z, nu.w);
    __half2 c = __floats2half2_rn(nv.x, nv.y);
    __half2 d = __floats2half2_rn(nv.z, nv.w);
    uint4 w;
    w.x = *reinterpret_cast<unsigned int*>(&a);
    w.y = *reinterpret_cast<unsigned int*>(&b);
    w.z = *reinterpret_cast<unsigned int*>(&c);
    w.w = *reinterpret_cast<unsigned int*>(&d);
    recW[slot] = w;
    invmap[uv] = (unsigned int)slot;
}

// ---------- K4: evalA — patch in registers, stream records, slot-ordered out ----------
__global__ __launch_bounds__(256) void evalA_kernel(
    const uint2* __restrict__ ctrlH, const uint4* __restrict__ recW,
    const int* __restrict__ hist, const int* __restrict__ base,
    ushort4* __restrict__ res)
{
    const int gid  = (blockIdx.x * 256 + threadIdx.x) >> 3;
    const int b    = threadIdx.x & 7;
    const int cell = gid / SPLIT;
    const int half = gid & (SPLIT - 1);
    if (cell >= NCELL) return;

    const int count = hist[cell * PADI];
    const int h0 = half * ((count + SPLIT - 1) / SPLIT);
    const int h1 = min(count, h0 + (count + SPLIT - 1) / SPLIT);
    if (h0 >= h1) return;

    const int us3 = cell / SP;
    const int vs3 = cell - us3 * SP;
    const int mybase = base[cell];

    // load patch once, convert to f32 registers (lane owns batch b)
    const uint2* cp = ctrlH + ((size_t)(us3 * ND + vs3) * 8 + b);
    float px[4][4], py[4][4], pz[4][4], pw[4][4];
    #pragma unroll
    for (int l = 0; l < 4; ++l) {
        #pragma unroll
        for (int r = 0; r < 4; ++r) {
            const uint2 h = cp[(l * ND + r) * 8];
            const float2 xy = __half22float2(*reinterpret_cast<const __half2*>(&h.x));
            const float2 zw = __half22float2(*reinterpret_cast<const __half2*>(&h.y));
            px[l][r] = xy.x; py[l][r] = xy.y; pz[l][r] = zw.x; pw[l][r] = zw.y;
        }
    }

    for (int i = h0; i < h1; ++i) {
        const int s = mybase + i;
        const uint4 w = recW[s];               // broadcast across 8 lanes
        const float2 nu01 = __half22float2(*reinterpret_cast<const __half2*>(&w.x));
        const float2 nu23 = __half22float2(*reinterpret_cast<const __half2*>(&w.y));
        const float2 nv01 = __half22float2(*reinterpret_cast<const __half2*>(&w.z));
        const float2 nv23 = __half22float2(*reinterpret_cast<const __half2*>(&w.w));
        const float nuL[4] = {nu01.x, nu01.y, nu23.x, nu23.y};
        const float nvL[4] = {nv01.x, nv01.y, nv23.x, nv23.y};

        float ax = 0.f, ay = 0.f, az = 0.f, aw = 0.f;
        #pragma unroll
        for (int l = 0; l < 4; ++l) {
            #pragma unroll
            for (int r = 0; r < 4; ++r) {
                const float wt = nuL[l] * nvL[r];
                ax = fmaf(wt, px[l][r], ax);
                ay = fmaf(wt, py[l][r], ay);
                az = fmaf(wt, pz[l][r], az);
                aw = fmaf(wt, pw[l][r], aw);
            }
        }
        const float inv = 1.0f / aw;
        ushort4 o;
        o.x = __half_as_ushort(__float2half(ax * inv));
        o.y = __half_as_ushort(__float2half(ay * inv));
        o.z = __half_as_ushort(__float2half(az * inv));
        o.w = 0;
        res[(size_t)s * 8 + b] = o;            // 8 lanes -> one full 64B line
    }
}

// ---------- K5: evalB — gather 1 line/point via invmap, coalesced store ----------
__global__ __launch_bounds__(256) void evalB_kernel(
    const ushort4* __restrict__ res, const unsigned int* __restrict__ invmap,
    float* __restrict__ out)
{
    __shared__ float rs[BD * 32 * 3];   // 3 KB
    const int tidx = threadIdx.x;
    const int b    = tidx & 7;
    const int uvL  = tidx >> 3;
    const int uv   = blockIdx.x * 32 + uvL;

    const unsigned int slot = invmap[uv];      // broadcast across 8 lanes
    const ushort4 h = res[(size_t)slot * 8 + b];

    float* rp = &rs[(b * 32 + uvL) * 3];
    rp[0] = __half2float(*reinterpret_cast<const __half*>(&h.x));
    rp[1] = __half2float(*reinterpret_cast<const __half*>(&h.y));
    rp[2] = __half2float(*reinterpret_cast<const __half*>(&h.z));
    __syncthreads();

    if (tidx < 192) {
        const int rb = tidx / 24;
        const int k  = tidx - rb * 24;
        const float4 v = reinterpret_cast<const float4*>(&rs[rb * 96])[k];
        float* dst = out + (size_t)rb * (UVN * 3) + (size_t)blockIdx.x * 96 + k * 4;
        *reinterpret_cast<float4*>(dst) = v;
    }
}

// ================= r5 fallback path (verified, 31.2 µs) =================
__global__ __launch_bounds__(256) void transpose_h_kernel(
    const float4* __restrict__ ctrl, ushort4* __restrict__ ctrlH)
{
    const int tid = blockIdx.x * blockDim.x + threadIdx.x;
    const int b   = tid & 7;
    const int mn  = tid >> 3;
    ctrlH[tid] = cvt4h(ctrl[b * (MD * ND) + mn]);
}

__global__ __launch_bounds__(256) void surfeval_h_kernel(
    const uint2* __restrict__ ctrlH,
    const float4* __restrict__ Nu4,
    const float4* __restrict__ Nv4,
    const int* __restrict__ uspan,
    const int* __restrict__ vspan,
    float* __restrict__ out)
{
    __shared__ float rs[BD * 32 * 3];
    const int tidx = threadIdx.x;
    const int b    = tidx & 7;
    const int uvL  = tidx >> 3;
    const int uv   = blockIdx.x * 32 + uvL;

    const int us = uspan[uv];
    const int vs = vspan[uv];
    const float4 nu = Nu4[uv];
    const float4 nv = Nv4[uv];
    const float nuL[4] = {nu.x, nu.y, nu.z, nu.w};
    const float nvL[4] = {nv.x, nv.y, nv.z, nv.w};

    const uint2* cp = ctrlH + ((size_t)((us - 3) * ND + (vs - 3)) * 8 + b);
    uint2 c[4][4];
    #pragma unroll
    for (int l = 0; l < 4; ++l) {
        const uint2* row = cp + l * (ND * 8);
        #pragma unroll
        for (int r = 0; r < 4; ++r) c[l][r] = row[r * 8];
    }
    float ax = 0.f, ay = 0.f, az = 0.f, aw = 0.f;
    #pragma unroll
    for (int l = 0; l < 4; ++l) {
        #pragma unroll
        for (int r = 0; r < 4; ++r) {
            const float w = nuL[l] * nvL[r];
            const float2 xy = __half22float2(*reinterpret_cast<const __half2*>(&c[l][r].x));
            const float2 zw = __half22float2(*reinterpret_cast<const __half2*>(&c[l][r].y));
            ax = fmaf(w, xy.x, ax); ay = fmaf(w, xy.y, ay);
            az = fmaf(w, zw.x, az); aw = fmaf(w, zw.y, aw);
        }
    }
    const float inv = 1.0f / aw;
    float* rp = &rs[(b * 32 + uvL) * 3];
    rp[0] = ax * inv; rp[1] = ay * inv; rp[2] = az * inv;
    __syncthreads();
    if (tidx < 192) {
        const int rb = tidx / 24;
        const int k  = tidx - rb * 24;
        const float4 v = reinterpret_cast<const float4*>(&rs[rb * 96])[k];
        float* dst = out + (size_t)rb * (UVN * 3) + (size_t)blockIdx.x * 96 + k * 4;
        *reinterpret_cast<float4*>(dst) = v;
    }
}

__global__ __launch_bounds__(256) void surfeval_naive_kernel(
    const float* __restrict__ ctrl, const float* __restrict__ Nu,
    const float* __restrict__ Nv, const int* __restrict__ uspan,
    const int* __restrict__ vspan, float* __restrict__ out)
{
    const int tid = blockIdx.x * blockDim.x + threadIdx.x;
    const int uv = tid & (UVN - 1);
    const int b  = tid >> 18;
    const int us = uspan[uv];
    const int vs = vspan[uv];
    const float4 nu = reinterpret_cast<const float4*>(Nu)[uv];
    const float4 nv = reinterpret_cast<const float4*>(Nv)[uv];
    const float nuL[4] = {nu.x, nu.y, nu.z, nu.w};
    const float nvL[4] = {nv.x, nv.y, nv.z, nv.w};
    const float4* cp = reinterpret_cast<const float4*>(ctrl)
                     + ((b * MD + (us - 3)) * ND + (vs - 3));
    float ax = 0.f, ay = 0.f, az = 0.f, aw = 0.f;
    #pragma unroll
    for (int l = 0; l < 4; ++l) {
        const float4* row = cp + l * ND;
        #pragma unroll
        for (int r = 0; r < 4; ++r) {
            const float w = nuL[l] * nvL[r];
            const float4 cc = row[r];
            ax = fmaf(w, cc.x, ax); ay = fmaf(w, cc.y, ay);
            az = fmaf(w, cc.z, az); aw = fmaf(w, cc.w, aw);
        }
    }
    const float inv = 1.0f / aw;
    float* o = out + (size_t)tid * 3;
    o[0] = ax * inv; o[1] = ay * inv; o[2] = az * inv;
}

extern "C" void kernel_launch(void* const* d_in, const int* in_sizes, int n_in,
                              void* d_out, int out_size, void* d_ws, size_t ws_size,
                              hipStream_t stream) {
    const float* ctrl  = (const float*)d_in[0];
    const float* Nu    = (const float*)d_in[1];
    const float* Nv    = (const float*)d_in[2];
    const int*   uspan = (const int*)d_in[3];
    const int*   vspan = (const int*)d_in[4];
    float* out = (float*)d_out;

    // ws layout (bytes)
    const size_t oCtrl = 0;                                   // 1,048,576
    const size_t oHist = 1048576;                             // 1,000,000 (15625*64)
    const size_t oCurs = oHist + 1000000;                     // 1,000,000
    const size_t oBase = oCurs + 1000000;                     // 62,500
    const size_t oRecW = (oBase + 62500 + 255) & ~(size_t)255;// UVN*16 = 4 MB
    const size_t oInv  = oRecW + (size_t)UVN * 16;            // UVN*4  = 1 MB
    const size_t oRes  = oInv  + (size_t)UVN * 4;             // UVN*64 = 16 MB
    const size_t wsReq = oRes  + (size_t)UVN * 64;            // ~24 MB total

    if (ws_size >= wsReq) {
        char* ws = (char*)d_ws;
        ushort4*      ctrlH  = (ushort4*)(ws + oCtrl);
        int*          hist   = (int*)(ws + oHist);
        int*          curs   = (int*)(ws + oCurs);
        int*          baseC  = (int*)(ws + oBase);
        uint4*        recW   = (uint4*)(ws + oRecW);
        unsigned int* invmap = (unsigned int*)(ws + oInv);
        ushort4*      res    = (ushort4*)(ws + oRes);

        hipMemsetAsync(ws + oHist, 0, 1000000, stream);
        prep_kernel<<<(MD * ND * BD + UVN) / 256, 256, 0, stream>>>(
            (const float4*)ctrl, ctrlH, uspan, vspan, hist);
        scan_kernel<<<1, 1024, 0, stream>>>(hist, baseC, curs);
        fill_kernel<<<UVN / 256, 256, 0, stream>>>(
            (const float4*)Nu, (const float4*)Nv, uspan, vspan,
            curs, recW, invmap);
        const int groups = NCELL * SPLIT;
        evalA_kernel<<<(groups * 8 + 255) / 256, 256, 0, stream>>>(
            (const uint2*)ctrlH, recW, hist, baseC, res);
        evalB_kernel<<<UVN / 32, 256, 0, stream>>>(res, invmap, out);
    } else if (ws_size >= (size_t)MD * ND * BD * 8) {
        ushort4* ctrlH = (ushort4*)d_ws;
        transpose_h_kernel<<<(MD * ND * BD) / 256, 256, 0, stream>>>(
            (const float4*)ctrl, ctrlH);
        surfeval_h_kernel<<<UVN / 32, 256, 0, stream>>>(
            (const uint2*)ctrlH, (const float4*)Nu, (const float4*)Nv,
            uspan, vspan, out);
    } else {
        surfeval_naive_kernel<<<(BD * UVN) / 256, 256, 0, stream>>>(
            ctrl, Nu, Nv, uspan, vspan, out);
    }
}

// Round 9
// 27.519 us; speedup vs baseline: 3.7083x; 3.6347x over previous
//
#include <hip/hip_runtime.h>
#include <hip/hip_fp16.h>

// SurfEval: B=8, M=128, N=128, ctrl 4ch, P=Q=3, OUT=512
// ctrl_pts : (8,128,128,4) f32; Nu/Nv: (512,512,4) f32; spans: (512,512) i32 in [3,127]
// out : (8,512,512,3) f32 = sw[...,:3]/sw[...,3:]
//
// Round-9: r5 structure, but thread = (uv, batch-PAIR). ctrlH is fp16 (m,n,b);
// a 16B dwordx4 covers 2 batches of one patch point -> gather instruction
// count and wave count halve vs r5; 64B segments/point unchanged.

#define OUTD 512
#define UVN  (OUTD * OUTD)   // 262144
#define MD   128
#define ND   128
#define BD   8

__device__ __forceinline__ ushort4 cvt4h(const float4 c) {
    ushort4 h;
    h.x = __half_as_ushort(__float2half(c.x));
    h.y = __half_as_ushort(__float2half(c.y));
    h.z = __half_as_ushort(__float2half(c.z));
    h.w = __half_as_ushort(__float2half(c.w));
    return h;
}

// ---------- transpose+convert: ctrl (b,m,n,4f32) -> ctrlH (m,n,b,4f16) ----------
__global__ __launch_bounds__(256) void transpose_h_kernel(
    const float4* __restrict__ ctrl, ushort4* __restrict__ ctrlH)
{
    const int tid = blockIdx.x * blockDim.x + threadIdx.x;  // 0 .. 131071
    const int b   = tid & 7;
    const int mn  = tid >> 3;
    ctrlH[tid] = cvt4h(ctrl[b * (MD * ND) + mn]);
}

// ---------- main: thread = (uv, bpair); 4 lanes/uv, 16B loads cover 2 batches ----
// Block 256 = 64 uv x 4 bpairs.
__global__ __launch_bounds__(256) void surfeval_h2_kernel(
    const uint4* __restrict__ ctrlH4,   // idx = (m*ND+n)*4 + bp  (16B units)
    const float4* __restrict__ Nu4,
    const float4* __restrict__ Nv4,
    const int* __restrict__ uspan,
    const int* __restrict__ vspan,
    float* __restrict__ out)
{
    __shared__ float rs[BD * 196];       // [b][padded 196] ~6.1 KB

    const int tidx = threadIdx.x;
    const int bp   = tidx & 3;           // batches 2bp, 2bp+1
    const int uvL  = tidx >> 2;          // 0..63
    const int uv   = blockIdx.x * 64 + uvL;

    const int us3 = uspan[uv] - 3;
    const int vs3 = vspan[uv] - 3;
    const float4 nu = Nu4[uv];
    const float4 nv = Nv4[uv];
    const float nuL[4] = {nu.x, nu.y, nu.z, nu.w};
    const float nvL[4] = {nv.x, nv.y, nv.z, nv.w};

    // patch point (l,r), batches (2bp,2bp+1): ctrlH4[((us3+l)*ND + vs3+r)*4 + bp]
    const uint4* cp = ctrlH4 + ((size_t)(us3 * ND + vs3) * 4 + bp);

    // ---- load phase: 16 independent dwordx4 (imm offsets within each row)
    uint4 c[4][4];
    #pragma unroll
    for (int l = 0; l < 4; ++l) {
        const uint4* row = cp + l * (ND * 4);
        #pragma unroll
        for (int r = 0; r < 4; ++r)
            c[l][r] = row[r * 4];
    }

    // ---- compute phase: two batches' accumulators
    float ax0 = 0.f, ay0 = 0.f, az0 = 0.f, aw0 = 0.f;
    float ax1 = 0.f, ay1 = 0.f, az1 = 0.f, aw1 = 0.f;
    #pragma unroll
    for (int l = 0; l < 4; ++l) {
        #pragma unroll
        for (int r = 0; r < 4; ++r) {
            const float w = nuL[l] * nvL[r];
            const float2 a01 = __half22float2(*reinterpret_cast<const __half2*>(&c[l][r].x));
            const float2 a23 = __half22float2(*reinterpret_cast<const __half2*>(&c[l][r].y));
            const float2 b01 = __half22float2(*reinterpret_cast<const __half2*>(&c[l][r].z));
            const float2 b23 = __half22float2(*reinterpret_cast<const __half2*>(&c[l][r].w));
            ax0 = fmaf(w, a01.x, ax0); ay0 = fmaf(w, a01.y, ay0);
            az0 = fmaf(w, a23.x, az0); aw0 = fmaf(w, a23.y, aw0);
            ax1 = fmaf(w, b01.x, ax1); ay1 = fmaf(w, b01.y, ay1);
            az1 = fmaf(w, b23.x, az1); aw1 = fmaf(w, b23.y, aw1);
        }
    }

    const float inv0 = 1.0f / aw0;
    const float inv1 = 1.0f / aw1;
    const int b0 = 2 * bp;
    float* r0 = &rs[b0 * 196 + uvL * 3];
    r0[0] = ax0 * inv0; r0[1] = ay0 * inv0; r0[2] = az0 * inv0;
    float* r1 = &rs[(b0 + 1) * 196 + uvL * 3];
    r1[0] = ax1 * inv1; r1[1] = ay1 * inv1; r1[2] = az1 * inv1;

    __syncthreads();

    // ---- store phase: 384 coalesced dwordx4 (per b: 64 uv x 3 = 768B run)
    #pragma unroll
    for (int k = tidx; k < 384; k += 256) {
        const int b = k / 48;
        const int j = k - b * 48;
        const float4 v = *reinterpret_cast<const float4*>(&rs[b * 196 + j * 4]);
        float* dst = out + (size_t)b * (UVN * 3) + (size_t)blockIdx.x * 192 + j * 4;
        *reinterpret_cast<float4*>(dst) = v;
    }
}

// ---------- fallback (verified round-1 kernel, no workspace needed) ----------
__global__ __launch_bounds__(256) void surfeval_naive_kernel(
    const float* __restrict__ ctrl, const float* __restrict__ Nu,
    const float* __restrict__ Nv, const int* __restrict__ uspan,
    const int* __restrict__ vspan, float* __restrict__ out)
{
    const int tid = blockIdx.x * blockDim.x + threadIdx.x;
    const int uv = tid & (UVN - 1);
    const int b  = tid >> 18;
    const int us = uspan[uv];
    const int vs = vspan[uv];
    const float4 nu = reinterpret_cast<const float4*>(Nu)[uv];
    const float4 nv = reinterpret_cast<const float4*>(Nv)[uv];
    const float nuL[4] = {nu.x, nu.y, nu.z, nu.w};
    const float nvL[4] = {nv.x, nv.y, nv.z, nv.w};
    const float4* cp = reinterpret_cast<const float4*>(ctrl)
                     + ((b * MD + (us - 3)) * ND + (vs - 3));
    float ax = 0.f, ay = 0.f, az = 0.f, aw = 0.f;
    #pragma unroll
    for (int l = 0; l < 4; ++l) {
        const float4* row = cp + l * ND;
        #pragma unroll
        for (int r = 0; r < 4; ++r) {
            const float w = nuL[l] * nvL[r];
            const float4 cc = row[r];
            ax = fmaf(w, cc.x, ax); ay = fmaf(w, cc.y, ay);
            az = fmaf(w, cc.z, az); aw = fmaf(w, cc.w, aw);
        }
    }
    const float inv = 1.0f / aw;
    float* o = out + (size_t)tid * 3;
    o[0] = ax * inv; o[1] = ay * inv; o[2] = az * inv;
}

extern "C" void kernel_launch(void* const* d_in, const int* in_sizes, int n_in,
                              void* d_out, int out_size, void* d_ws, size_t ws_size,
                              hipStream_t stream) {
    const float* ctrl  = (const float*)d_in[0];
    const float* Nu    = (const float*)d_in[1];
    const float* Nv    = (const float*)d_in[2];
    const int*   uspan = (const int*)d_in[3];
    const int*   vspan = (const int*)d_in[4];
    float* out = (float*)d_out;

    const size_t ctrlH_bytes = (size_t)MD * ND * BD * 8;   // 1 MB fp16

    if (ws_size >= ctrlH_bytes) {
        ushort4* ctrlH = (ushort4*)d_ws;
        transpose_h_kernel<<<(MD * ND * BD) / 256, 256, 0, stream>>>(
            (const float4*)ctrl, ctrlH);
        surfeval_h2_kernel<<<UVN / 64, 256, 0, stream>>>(
            (const uint4*)ctrlH, (const float4*)Nu, (const float4*)Nv,
            uspan, vspan, out);
    } else {
        surfeval_naive_kernel<<<(BD * UVN) / 256, 256, 0, stream>>>(
            ctrl, Nu, Nv, uspan, vspan, out);
    }
}